// Round 4
// baseline (866.825 us; speedup 1.0000x reference)
//
#include <hip/hip_runtime.h>
#include <cstdint>
#include <cstddef>

// ============================================================================
// LSTMCellQ. Round 9 == Round 8 resubmit (round-8 bench died at container
// level before compile/run; audit found no kernel-side hang hazard).
//  - gemm_mfma: B (hi/lo) fragments load global->VGPR directly (prefetch
//    distance 1, compiler-tracked waits). LDS stages A only (3 x 8 KiB,
//    depth-2 DMA, steady-state s_waitcnt vmcnt(2)). Per-step LDS demand
//    ~510 -> ~250 cyc < MFMA 326 cyc.  A-swizzle unchanged (r6-verified).
//  - gemm_p0: T0 block slice (32 KiB) staged once in LDS; inner loop reads
//    are uniform-address broadcasts (was 2048 redundant vmem/thread).
//    FMA order bit-identical.
//  - all numerics bit-identical to round 6/7 (verified absmax 0.0).
// Round-5 lattice analysis unchanged: only ih plane-0 bit-exact (gemm_p0 f32);
// hh m=0..3 + ih m=1..3 via i16-grid (1/6144) hi/lo i8 MFMA, integer combine.
// RNG (verified): threefry partitionable, foldlike split, bits=x0^x1,
// CHLO Giles erfinv f32, device logf, rintf round-half-even.
// ============================================================================

typedef int v4i __attribute__((ext_vector_type(4)));

struct KPc { uint32_t a, b; };

__host__ __device__ constexpr KPc ctf(uint32_t k0, uint32_t k1v, uint32_t c0, uint32_t c1) {
  uint32_t ks2 = k0 ^ k1v ^ 0x1BD11BDAu;
  uint32_t x0 = c0 + k0;
  uint32_t x1 = c1 + k1v;
  uint32_t r0[4] = {13u, 15u, 26u, 6u};
  uint32_t r1[4] = {17u, 29u, 16u, 24u};
  uint32_t ks[3] = {k0, k1v, ks2};
  for (int g = 0; g < 5; ++g) {
    for (int j = 0; j < 4; ++j) {
      uint32_t rr = (g & 1) ? r1[j] : r0[j];
      x0 += x1;
      x1 = (x1 << rr) | (x1 >> (32u - rr));
      x1 ^= x0;
    }
    x0 += ks[(g + 1) % 3];
    x1 += ks[(g + 2) % 3] + (uint32_t)(g + 1);
  }
  return KPc{x0, x1};
}

constexpr KPc K1K  = ctf(0u, 42u, 0u, 0u);
constexpr KPc K2K  = ctf(0u, 42u, 0u, 1u);
constexpr KPc KWIH = ctf(K1K.a, K1K.b, 0u, 0u);
constexpr KPc KBIH = ctf(K1K.a, K1K.b, 0u, 1u);
constexpr KPc KWHH = ctf(K2K.a, K2K.b, 0u, 0u);
constexpr KPc KBHH = ctf(K2K.a, K2K.b, 0u, 1u);

__device__ __forceinline__ uint32_t tf_bits(uint32_t k0, uint32_t k1v, uint32_t j) {
  KPc r = ctf(k0, k1v, 0u, j);
  return r.a ^ r.b;
}

// ---------------- float max-reduction with order-encoded uint ----------------
__device__ __forceinline__ unsigned encf(float f) {
  unsigned u = __float_as_uint(f);
  return (u & 0x80000000u) ? ~u : (u | 0x80000000u);
}
__device__ __forceinline__ float decf(unsigned e) {
  unsigned u = (e & 0x80000000u) ? (e & 0x7FFFFFFFu) : ~e;
  return __uint_as_float(u);
}

__global__ void rmax_kernel(const float* __restrict__ x, int n, unsigned* __restrict__ out) {
  unsigned best = 0u;
  for (int i = blockIdx.x * blockDim.x + threadIdx.x; i < n; i += gridDim.x * blockDim.x) {
    unsigned e = encf(x[i]);
    best = best > e ? best : e;
  }
  for (int off = 32; off > 0; off >>= 1) {
    unsigned o = __shfl_down(best, off, 64);
    best = best > o ? best : o;
  }
  __shared__ unsigned sm[4];
  int lane = threadIdx.x & 63, wv = threadIdx.x >> 6;
  if (lane == 0) sm[wv] = best;
  __syncthreads();
  if (threadIdx.x == 0) {
    unsigned b = sm[0];
    for (int i = 1; i < 4; ++i) b = b > sm[i] ? b : sm[i];
    atomicMax(out, b);
  }
}

// ---------------- XLA-replicated erfinv / uniform->normal ----------------
__device__ __forceinline__ float xla_log1p(float t) {
  float small = __fmul_rn(__fadd_rn(__fmul_rn(-0.5f, t), 1.0f), t);
  float large = logf(__fadd_rn(t, 1.0f));
  return (fabsf(t) < 1e-4f) ? small : large;
}

__device__ __forceinline__ float xla_erfinv(float x) {
  float w = -xla_log1p(-__fmul_rn(x, x));
  float p;
  if (w < 5.0f) {
    float ww = __fadd_rn(w, -2.5f);
    p = 2.81022636e-08f;
    p = __fadd_rn(3.43273939e-07f, __fmul_rn(p, ww));
    p = __fadd_rn(-3.5233877e-06f, __fmul_rn(p, ww));
    p = __fadd_rn(-4.39150654e-06f, __fmul_rn(p, ww));
    p = __fadd_rn(0.00021858087f, __fmul_rn(p, ww));
    p = __fadd_rn(-0.00125372503f, __fmul_rn(p, ww));
    p = __fadd_rn(-0.00417768164f, __fmul_rn(p, ww));
    p = __fadd_rn(0.246640727f, __fmul_rn(p, ww));
    p = __fadd_rn(1.50140941f, __fmul_rn(p, ww));
  } else {
    float ww = __fadd_rn(sqrtf(w), -3.0f);
    p = -0.000200214257f;
    p = __fadd_rn(0.000100950558f, __fmul_rn(p, ww));
    p = __fadd_rn(0.00134934322f, __fmul_rn(p, ww));
    p = __fadd_rn(-0.00367342844f, __fmul_rn(p, ww));
    p = __fadd_rn(0.00573950773f, __fmul_rn(p, ww));
    p = __fadd_rn(-0.0076224613f, __fmul_rn(p, ww));
    p = __fadd_rn(0.00943887047f, __fmul_rn(p, ww));
    p = __fadd_rn(1.00167406f, __fmul_rn(p, ww));
    p = __fadd_rn(2.83297682f, __fmul_rn(p, ww));
  }
  return __fmul_rn(p, x);
}

__device__ __forceinline__ float normal_from_bits(uint32_t bits) {
  float u01 = __uint_as_float((bits >> 9) | 0x3f800000u) - 1.0f;
  const float lo = -0x1.fffffep-1f;
  float u = fmaxf(lo, __fadd_rn(__fmul_rn(u01, 2.0f), lo));
  return __fmul_rn(0x1.6a09e6p+0f, xla_erfinv(u));
}

__device__ __forceinline__ float quantw(float x) {
  float xs = fminf(fmaxf(x, -0.9921875f), 0.9921875f);
  return __fmul_rn(rintf(__fmul_rn(xs, 128.0f)), 0.0078125f);
}

// ---------------- ih plane-0: noisy f32 terms T0[k][col] ----------------
__global__ void gen_t0_kernel(const float* __restrict__ W, float* __restrict__ T0,
                              const unsigned* __restrict__ encp) {
  int j = blockIdx.x * 256 + threadIdx.x;     // < 1048576 = 256k x 4096c (m=0)
  if (j >= 1048576) return;
  float wmax = decf(*encp);
  float nrm = normal_from_bits(tf_bits(KWIH.a, KWIH.b, (uint32_t)j));
  float nw = __fmul_rn(__fmul_rn(nrm, wmax), 0.1f);
  T0[j] = __fadd_rn(quantw(W[j]), nw);
}

__global__ void gen_bias_kernel(const float* __restrict__ bsrc, float* __restrict__ bq,
                                float* __restrict__ nb, int n,
                                const unsigned* __restrict__ encp, uint32_t k0, uint32_t k1v) {
  int j = blockIdx.x * 256 + threadIdx.x;
  if (j >= n) return;
  float bmax = decf(*encp);
  float nrm = normal_from_bits(tf_bits(k0, k1v, (uint32_t)j));
  bq[j] = quantw(bsrc[j]);
  nb[j] = __fmul_rn(__fmul_rn(nrm, bmax), 0.1f);
}

// ---------------- ih bitplane nibbles [k][row], LDS-transposed ---------------
// Reads x[b][i] coalesced in i; writes kvT[i*4096+b] coalesced in b.
__global__ __launch_bounds__(256) void kv_kernel(
    const float* __restrict__ x, const float* __restrict__ ap,
    const float* __restrict__ offp, unsigned char* __restrict__ kvT, int Kdim) {
  __shared__ unsigned char tile[64][65];
  const int tid = threadIdx.x;
  const int bt = blockIdx.x * 64, it = blockIdx.y * 64;
  const float a = ap[0], off = offp[0];
#pragma unroll
  for (int e = 0; e < 16; ++e) {
    int idx = e * 256 + tid;
    int bl = idx >> 6, il = idx & 63;
    float v = fmaxf(-a, fminf(x[(size_t)(bt + bl) * Kdim + it + il], a));
    float t = __fdiv_rn(__fadd_rn(v, off), __fmul_rn(a, 2.0f));
    int k = (int)rintf(__fmul_rn(15.0f, t));
    tile[il][bl] = (unsigned char)(k & 15);
  }
  __syncthreads();
#pragma unroll
  for (int e = 0; e < 16; ++e) {
    int idx = e * 256 + tid;
    int il = idx >> 6, bl = idx & 63;
    kvT[(size_t)(it + il) * 4096 + bt + bl] = tile[il][bl];
  }
}

// ---------------- hh bit planes i8 [m][row][k] ----------------
__global__ void gen_ahh_kernel(const float* __restrict__ hx, const float* __restrict__ a11p,
                               const float* __restrict__ a1p, signed char* __restrict__ A) {
  int j = blockIdx.x * 256 + threadIdx.x;   // row*1024 + k
  if (j >= 4096 * 1024) return;
  float a = a11p[0], off = a1p[0];
  float v = fmaxf(-a, fminf(hx[j], a));
  float t = __fdiv_rn(__fadd_rn(v, off), __fmul_rn(a, 2.0f));
  int kq = (int)rintf(__fmul_rn(15.0f, t));
  A[j]                      = (signed char)((kq >> 3) & 1);
  A[(size_t)(1 << 22) + j]  = (signed char)((kq >> 2) & 1);
  A[(size_t)(2 << 22) + j]  = (signed char)((kq >> 1) & 1);
  A[(size_t)(3 << 22) + j]  = (signed char)(kq & 1);
}

// ---------------- ih bit planes 1..3 i8 [m-1][row][k] ----------------
__global__ void gen_aih_kernel(const float* __restrict__ input, const float* __restrict__ a1p,
                               signed char* __restrict__ A) {
  int j = blockIdx.x * 256 + threadIdx.x;   // row*256 + k
  if (j >= 4096 * 256) return;
  float a = a1p[0];
  float v = fmaxf(-a, fminf(input[j], a));
  float t = __fdiv_rn(__fadd_rn(v, a), __fmul_rn(a, 2.0f));
  int kq = (int)rintf(__fmul_rn(15.0f, t));
  A[j]                  = (signed char)((kq >> 2) & 1);   // m=1
  A[1048576 + j]        = (signed char)((kq >> 1) & 1);   // m=2
  A[2097152 + j]        = (signed char)(kq & 1);          // m=3
}

// ---------------- quantized noisy weights -> hi/lo i8 [part][plane][col][k] ---
// Coalesced W reads and coalesced [col][k] stores via LDS 64x64 transpose.
__global__ __launch_bounds__(256) void gen_bt_kernel(
    const float* __restrict__ W, signed char* __restrict__ Bt,
    const unsigned* __restrict__ encp, int K, int m0, int nPlanes,
    uint32_t k0k, uint32_t k1k) {
  __shared__ signed char lhi[64 * 68];
  __shared__ signed char llo[64 * 68];
  const int tid = threadIdx.x;
  const int m = m0 + blockIdx.z;
  const int kt = blockIdx.y * 64, ct = blockIdx.x * 64;
  const float wmax = decf(*encp);
#pragma unroll 4
  for (int i = 0; i < 16; ++i) {
    int e = i * 256 + tid;
    int kl = e >> 6, cl = e & 63;
    uint32_t j = (uint32_t)(((m * K + kt + kl) << 12) + ct + cl);
    float nrm = normal_from_bits(tf_bits(k0k, k1k, j));
    float t = __fadd_rn(quantw(W[j]), __fmul_rn(__fmul_rn(nrm, wmax), 0.1f));
    int ti = (int)rintf(__fmul_rn(t, 6144.0f));
    int hi = (ti + 128) >> 8;
    int lo = ti - (hi << 8);
    lhi[cl * 68 + kl] = (signed char)hi;
    llo[cl * 68 + kl] = (signed char)lo;
  }
  __syncthreads();
  const size_t planeElems = (size_t)K << 12;
  signed char* bh = Bt + (size_t)blockIdx.z * planeElems;
  signed char* bl = Bt + (size_t)(nPlanes + blockIdx.z) * planeElems;
#pragma unroll 4
  for (int i = 0; i < 16; ++i) {
    int f = i * 256 + tid;
    int cl = f >> 6, kl = f & 63;
    size_t o = (size_t)(ct + cl) * K + kt + kl;
    bh[o] = lhi[cl * 68 + kl];
    bl[o] = llo[cl * 68 + kl];
  }
}

// ---------------- ih plane-0 GEMM: bit-exact f32, LDS-broadcast t feed -------
// T0 block slice (256 k x 32 cols = 32 KiB) staged once in LDS; inner-loop
// reads are wave-uniform broadcasts. FMA order identical to round 5.
__global__ __launch_bounds__(256) void gemm_p0_kernel(
    const float* __restrict__ T0, const float* __restrict__ bq, const float* __restrict__ nb,
    const unsigned char* __restrict__ kvT, unsigned char* __restrict__ Kp) {
  __shared__ __align__(16) float lt[256 * 32];
  const int tid = threadIdx.x, lane = tid & 63, wv = tid >> 6;
  const int c0 = blockIdx.x * 32;
  const int row = blockIdx.y * 256 + wv * 64 + lane;

#pragma unroll
  for (int e = 0; e < 32; ++e) {
    int idx = e * 256 + tid;                 // k = idx>>5, c = idx&31
    lt[idx] = T0[((size_t)(idx >> 5) << 12) + c0 + (idx & 31)];
  }
  __syncthreads();

  float acc[32];
#pragma unroll
  for (int j = 0; j < 32; ++j) acc[j] = 0.0f;

  const unsigned char* kvp = kvT + row;
#pragma unroll 2
  for (int k = 0; k < 256; ++k) {
    unsigned nib = kvp[(size_t)k << 12];
    float f = (float)((nib >> 3) & 1u);
    const float4* tp = (const float4*)(lt + (k << 5));
    float4 tv[8];
#pragma unroll
    for (int q = 0; q < 8; ++q) tv[q] = tp[q];
#pragma unroll
    for (int q = 0; q < 8; ++q) {
      acc[q * 4 + 0] = __builtin_fmaf(f, tv[q].x, acc[q * 4 + 0]);
      acc[q * 4 + 1] = __builtin_fmaf(f, tv[q].y, acc[q * 4 + 1]);
      acc[q * 4 + 2] = __builtin_fmaf(f, tv[q].z, acc[q * 4 + 2]);
      acc[q * 4 + 3] = __builtin_fmaf(f, tv[q].w, acc[q * 4 + 3]);
    }
  }

#pragma unroll
  for (int j = 0; j < 32; ++j) {
    int col = c0 + j;
    float s = __fadd_rn(__fadd_rn(acc[j], bq[col]), nb[col]);
    Kp[((size_t)row << 12) + col] = (s > 0.5f) ? (unsigned char)8 : (unsigned char)0;
  }
}

// ---------------- i8 MFMA GEMM: 7 sub-problems, A-in-LDS, B-in-regs ----------
// Block tile 128x64, wave tile 64x32. LDS: 3 x 8 KiB (A only, XOR-swizzled,
// r6-verified). B hi/lo fragments load global->VGPR, prefetch distance 1.
// Steady-state wait: s_waitcnt vmcnt(2) leaves only A(t+1)'s 2 DMA loads in
// flight across the barrier. A(t) is always >=6-deep at the wait (drained
// under any intra-region reorder); B-register loads are compiler-tracked.
typedef __attribute__((address_space(3))) signed char lds_i8;
typedef __attribute__((address_space(1))) const signed char g_i8;

__device__ __forceinline__ void glds16(const signed char* g, signed char* l) {
  __builtin_amdgcn_global_load_lds((g_i8*)g, (lds_i8*)l, 16, 0, 0);
}

__global__ __launch_bounds__(256, 3) void gemm_mfma_kernel(
    const signed char* __restrict__ Ahh, const signed char* __restrict__ Bthh,
    const signed char* __restrict__ Aih, const signed char* __restrict__ Btih,
    const float* __restrict__ bqh, const float* __restrict__ nbh,
    const float* __restrict__ bqi, const float* __restrict__ nbi,
    unsigned char* __restrict__ Kp) {
  const int tid = threadIdx.x;
  const int lane = tid & 63, wv = tid >> 6;
  const int col0 = blockIdx.x * 64;
  const int row0 = blockIdx.y * 128;
  const int wrow = (wv >> 1) * 64;   // 0 / 64
  const int wcol = (wv & 1) * 32;    // 0 / 32

  // A tile 128 rows x 64 K bytes per buffer, triple-buffered
  __shared__ __align__(16) signed char smbuf[3][8192];

  const int l15 = lane & 15;
  const int cc  = (((lane >> 4) ^ ((lane >> 1) & 3)) << 4);        // frag-read chunk byte
  const int xq  = ((((lane & 3) ^ ((lane >> 3) & 3))) << 4);       // stage source chunk byte
  const int lr  = lane >> 2;                                       // stage local row 0..15
  const int kch = (lane >> 4) << 4;                                // B frag K-chunk byte

  uint32_t k12[4][2];
#pragma unroll
  for (int rf = 0; rf < 4; ++rf) { k12[rf][0] = 0u; k12[rf][1] = 0u; }

  for (int sub = 0; sub < 7; ++sub) {
    int K, w;
    const signed char *A, *Bh, *Bl;
    const float *bqp, *nbp;
    if (sub < 4) {                       // hh plane m = sub
      int m = sub;
      K = 1024;
      A  = Ahh  + ((size_t)m << 22);
      Bh = Bthh + ((size_t)m << 22);
      Bl = Bthh + ((size_t)(4 + m) << 22);
      bqp = bqh + (m << 12); nbp = nbh + (m << 12);
      w = (1 << (3 - m)) << 4;
    } else {                             // ih plane m = sub-3 (1..3)
      int m = sub - 3;
      K = 256;
      A  = Aih  + ((size_t)(m - 1) << 20);
      Bh = Btih + ((size_t)(m - 1) << 20);
      Bl = Btih + ((size_t)(3 + m - 1) << 20);
      bqp = bqi + (m << 12); nbp = nbi + (m << 12);
      w = 1 << (3 - m);
    }

    // A stage source pointers (pre-swizzled chunks; r6-verified layout)
    const size_t soff = (size_t)lr * K + xq;
    const signed char* gA  = A  + (size_t)(row0 + 32 * wv) * K + soff;
    const signed char* gA2 = gA + (size_t)16 * K;
    // B fragment base pointers (per-lane, straight layout)
    const signed char* pBh = Bh + (size_t)(col0 + wcol + l15) * K + kch;
    const signed char* pBl = Bl + (size_t)(col0 + wcol + l15) * K + kch;

    auto stageA = [&](signed char* base, int k0) {
      glds16(gA  + k0, base + (32 * wv) * 64);
      glds16(gA2 + k0, base + (32 * wv + 16) * 64);
    };

    v4i ach[4][2], acl[4][2];
    v4i zero = {0, 0, 0, 0};
#pragma unroll
    for (int rf = 0; rf < 4; ++rf)
#pragma unroll
      for (int cf = 0; cf < 2; ++cf) { ach[rf][cf] = zero; acl[rf][cf] = zero; }

    signed char* bc = &smbuf[0][0];      // current (tile t)
    signed char* bn = &smbuf[1][0];      // next (tile t+1)
    signed char* bf = &smbuf[2][0];      // free (target for tile t+2)

    const int nt = K >> 6;               // 16 or 4, always even

    v4i b0h[2], b0l[2], b1h[2], b1l[2];

    // prologue: A(0) DMA, B(0) regs, A(1) DMA  -> 8 vmem outstanding
    stageA(bc, 0);
    __builtin_amdgcn_sched_barrier(0);
#pragma unroll
    for (int cf = 0; cf < 2; ++cf) {
      b0h[cf] = *(const v4i*)(pBh + (size_t)cf * 16 * K);
      b0l[cf] = *(const v4i*)(pBl + (size_t)cf * 16 * K);
    }
    __builtin_amdgcn_sched_barrier(0);
    stageA(bn, 64);

    auto body = [&](int t, v4i (&uh)[2], v4i (&ul)[2], v4i (&lh)[2], v4i (&ll)[2]) {
      if (t + 1 < nt) {
        asm volatile("s_waitcnt vmcnt(2)" ::: "memory");   // A(t),B(t) done; A(t+1) flies
      } else {
        asm volatile("s_waitcnt vmcnt(0)" ::: "memory");   // last tile: full drain
      }
      __builtin_amdgcn_s_barrier();
      __builtin_amdgcn_sched_barrier(0);
      if (t + 1 < nt) {                                    // B(t+1) -> regs
        int k0 = (t + 1) << 6;
#pragma unroll
        for (int cf = 0; cf < 2; ++cf) {
          lh[cf] = *(const v4i*)(pBh + (size_t)cf * 16 * K + k0);
          ll[cf] = *(const v4i*)(pBl + (size_t)cf * 16 * K + k0);
        }
      }
      __builtin_amdgcn_sched_barrier(0);
      if (t + 2 < nt) stageA(bf, (t + 2) << 6);            // A(t+2) DMA across barriers
      __builtin_amdgcn_sched_barrier(0);

      v4i af[4];
#pragma unroll
      for (int rf = 0; rf < 4; ++rf)
        af[rf] = *(const v4i*)(bc + (wrow + rf * 16 + l15) * 64 + cc);
#pragma unroll
      for (int rf = 0; rf < 4; ++rf)
#pragma unroll
        for (int cf = 0; cf < 2; ++cf) {
          ach[rf][cf] = __builtin_amdgcn_mfma_i32_16x16x64_i8(af[rf], uh[cf], ach[rf][cf], 0, 0, 0);
          acl[rf][cf] = __builtin_amdgcn_mfma_i32_16x16x64_i8(af[rf], ul[cf], acl[rf][cf], 0, 0, 0);
        }
      signed char* tmp = bc; bc = bn; bn = bf; bf = tmp;   // rotate A buffers
    };

    for (int t = 0; t < nt; t += 2) {
      body(t,     b0h, b0l, b1h, b1l);
      body(t + 1, b1h, b1l, b0h, b0l);
    }
    __syncthreads();                     // sub boundary: reads done, safe restage

    // epilogue: float math bit-identical to round 5; pack decision bits per r
#pragma unroll
    for (int cf = 0; cf < 2; ++cf) {
      int col = col0 + wcol + cf * 16 + l15;
      float bqc = bqp[col];
      float nbc = nbp[col];
#pragma unroll
      for (int rf = 0; rf < 4; ++rf)
#pragma unroll
        for (int r = 0; r < 4; ++r) {
          int tot = ach[rf][cf][r] * 256 + acl[rf][cf][r];
          float s = __fmul_rn((float)tot, (1.0f / 6144.0f));
          float s2 = __fadd_rn(__fadd_rn(s, bqc), nbc);
          if (s2 > 0.5f) k12[rf][cf] += ((uint32_t)w << (8 * r));
        }
    }
  }

  // RMW-or bits into Kp (plane-0 kernel already stored bit 3; stream-ordered)
#pragma unroll
  for (int rf = 0; rf < 4; ++rf)
#pragma unroll
    for (int cf = 0; cf < 2; ++cf)
#pragma unroll
      for (int r = 0; r < 4; ++r) {
        int row = row0 + wrow + rf * 16 + ((lane >> 4) << 2) + r;
        int col = col0 + wcol + cf * 16 + l15;
        size_t o = ((size_t)row << 12) + col;
        Kp[o] = (unsigned char)(Kp[o] | ((k12[rf][cf] >> (8 * r)) & 255u));
      }
}

// ---------------- elementwise tail (verified absmax 0) ----------------
__device__ __forceinline__ float quant8(float x, float r) {
  float xs = __fdiv_rn(x, r);
  xs = fminf(fmaxf(xs, -0.9921875f), 0.9921875f);
  float q = rintf(__fmul_rn(xs, 128.0f));
  return __fmul_rn(__fdiv_rn(q, 128.0f), r);
}
__device__ __forceinline__ float pactf(float x, float a) { return fminf(fmaxf(x, -a), a); }
__device__ __forceinline__ double sigd(double x) { return 1.0 / (1.0 + exp(-x)); }

__global__ void tail_kernel(const unsigned char* __restrict__ Kp, const float* __restrict__ cx,
                            const float* a1p, const float* a3p, const float* a4p,
                            const float* a5p, const float* a6p, const float* a7p,
                            const float* a8p, const float* a9p, const float* a10p,
                            const float* a11p, float* __restrict__ out) {
  int idx = blockIdx.x * 256 + threadIdx.x;
  if (idx >= 4096 * 1024) return;
  int b = idx >> 10, h = idx & 1023;
  double a1 = (double)a1p[0], a11 = (double)a11p[0];
  const unsigned char* row = Kp + (size_t)b * 4096 + h;
  int pI = row[0], pJ = row[1024], pF = row[2048], pO = row[3072];
  auto gate = [&](int pk) -> double {
    double s1 = (double)(pk & 15) * (1.0 / 15.0);
    double s2 = (double)(pk >> 4) * (1.0 / 15.0);
    return (s1 * (2.0 * a1) - a1) + (s2 * (2.0 * a11) - a11);
  };
  double gi = gate(pI), gj = gate(pJ), gf = gate(pF), go = gate(pO);
  float a3 = a3p[0], a4 = a4p[0], a5 = a5p[0], a6 = a6p[0];
  float a7 = a7p[0], a8 = a8p[0], a9 = a9p[0], a10 = a10p[0], a11f = a11p[0];
  float fg  = quant8(pactf((float)sigd(gf), a3), a3);
  float ig  = quant8(pactf((float)sigd(gi), a4), a4);
  float act = quant8(pactf((float)tanh(gj), a5), a5);
  float og  = quant8(pactf((float)sigd(go), a6), a6);
  float cxv = cx[idx];
  float gc  = quant8(pactf(__fmul_rn(cxv, fg), a7), a7);
  float ai  = quant8(pactf(__fmul_rn(ig, act), a8), a8);
  float nc  = quant8(pactf(__fadd_rn(gc, ai), a9), a9);
  float ac  = quant8(pactf((float)tanh((double)nc), a10), a10);
  float nh  = quant8(pactf(__fmul_rn(ac, og), a11f), a11f);
  out[idx] = nh;
  out[4194304 + idx] = nc;
}

// ============================================================================
extern "C" void kernel_launch(void* const* d_in, const int* in_sizes, int n_in,
                              void* d_out, int out_size, void* d_ws, size_t ws_size,
                              hipStream_t stream) {
  const float* input = (const float*)d_in[0];
  const float* hx    = (const float*)d_in[1];
  const float* cx    = (const float*)d_in[2];
  const float* wih   = (const float*)d_in[3];
  const float* whh   = (const float*)d_in[4];
  const float* bih   = (const float*)d_in[5];
  const float* bhh   = (const float*)d_in[6];
  const float* a1p   = (const float*)d_in[7];
  const float* a3p   = (const float*)d_in[8];
  const float* a4p   = (const float*)d_in[9];
  const float* a5p   = (const float*)d_in[10];
  const float* a6p   = (const float*)d_in[11];
  const float* a7p   = (const float*)d_in[12];
  const float* a8p   = (const float*)d_in[13];
  const float* a9p   = (const float*)d_in[14];
  const float* a10p  = (const float*)d_in[15];
  const float* a11p  = (const float*)d_in[16];

  char* ws = (char*)d_ws;
  unsigned* enc        = (unsigned*)ws;                            // 256 B
  float* T0            = (float*)(ws + 256);                       // 4 MiB  [256][4096]
  float* bq_ih         = (float*)(ws + 256 + 4194304);             // 64 KiB x4
  float* nb_ih         = bq_ih + 16384;
  float* bq_hh         = nb_ih + 16384;
  float* nb_hh         = bq_hh + 16384;
  unsigned char* kv_ih = (unsigned char*)(nb_hh + 16384);          // 1 MiB [256][4096]
  signed char* A_hh    = (signed char*)(kv_ih + 1048576);          // 16 MiB [4][4096][1024]
  signed char* Bt_hh   = A_hh + 16777216;                          // 32 MiB [2][4][4096][1024]
  signed char* A_ih    = Bt_hh + 33554432;                         // 3 MiB [3][4096][256]
  signed char* Bt_ih   = A_ih + 3145728;                           // 6 MiB [2][3][4096][256]
  unsigned char* Kp    = (unsigned char*)(Bt_ih + 6291456);        // 16 MiB
  // total ~78.3 MiB

  hipMemsetAsync(enc, 0, 64, stream);
  rmax_kernel<<<512, 256, 0, stream>>>(wih, 4 * 256 * 4096, enc + 0);
  rmax_kernel<<<512, 256, 0, stream>>>(whh, 4 * 1024 * 4096, enc + 1);
  rmax_kernel<<<64, 256, 0, stream>>>(bih, 16384, enc + 2);
  rmax_kernel<<<64, 256, 0, stream>>>(bhh, 16384, enc + 3);

  kv_kernel<<<dim3(64, 4), 256, 0, stream>>>(input, a1p, a1p, kv_ih, 256);
  gen_aih_kernel<<<4096, 256, 0, stream>>>(input, a1p, A_ih);
  gen_ahh_kernel<<<16384, 256, 0, stream>>>(hx, a11p, a1p, A_hh);

  gen_bias_kernel<<<64, 256, 0, stream>>>(bih, bq_ih, nb_ih, 16384, enc + 2, KBIH.a, KBIH.b);
  gen_bias_kernel<<<64, 256, 0, stream>>>(bhh, bq_hh, nb_hh, 16384, enc + 3, KBHH.a, KBHH.b);

  gen_t0_kernel<<<4096, 256, 0, stream>>>(wih, T0, enc + 0);
  gen_bt_kernel<<<dim3(64, 16, 4), 256, 0, stream>>>(whh, Bt_hh, enc + 1, 1024, 0, 4,
                                                     KWHH.a, KWHH.b);
  gen_bt_kernel<<<dim3(64, 4, 3), 256, 0, stream>>>(wih, Bt_ih, enc + 0, 256, 1, 3,
                                                    KWIH.a, KWIH.b);

  gemm_p0_kernel<<<dim3(128, 16), 256, 0, stream>>>(T0, bq_ih, nb_ih, kv_ih, Kp);
  gemm_mfma_kernel<<<dim3(64, 32), 256, 0, stream>>>(A_hh, Bt_hh, A_ih, Bt_ih,
                                                     bq_hh, nb_hh, bq_ih, nb_ih, Kp);

  tail_kernel<<<16384, 256, 0, stream>>>(Kp, cx, a1p, a3p, a4p, a5p, a6p, a7p, a8p, a9p,
                                         a10p, a11p, (float*)d_out);
}

// Round 5
// 582.118 us; speedup vs baseline: 1.4891x; 1.4891x over previous
//
#include <hip/hip_runtime.h>
#include <cstdint>
#include <cstddef>

// ============================================================================
// LSTMCellQ. Round 10: revert gemm_mfma+gemm_p0 to r7-measured code (193us;
// r9's B-in-VGPR was -1.8x: uncoalesced 16-segment B loads + 1-iter cover).
// New this round (low-risk):
//  - launch fusion 14 -> 6: rmax_all (4 segments), prep_all (kv/aih/ahh/
//    bias*2/t0/bt*2 merged by block-range; sub-kernels independent).
//  - tail: gate values take only 256 lattice points, nc only 255 -> LDS
//    tables for all double transcendentals (identical expressions, bit-exact),
//    grid-stride 2048 blocks. Per-element: lookups + f32 chain only.
// Round-5 lattice analysis unchanged: only ih plane-0 bit-exact (gemm_p0 f32);
// hh m=0..3 + ih m=1..3 via i16-grid (1/6144) hi/lo i8 MFMA, integer combine.
// RNG (verified): threefry partitionable, foldlike split, bits=x0^x1,
// CHLO Giles erfinv f32, device logf, rintf round-half-even.
// ============================================================================

typedef int v4i __attribute__((ext_vector_type(4)));

struct KPc { uint32_t a, b; };

__host__ __device__ constexpr KPc ctf(uint32_t k0, uint32_t k1v, uint32_t c0, uint32_t c1) {
  uint32_t ks2 = k0 ^ k1v ^ 0x1BD11BDAu;
  uint32_t x0 = c0 + k0;
  uint32_t x1 = c1 + k1v;
  uint32_t r0[4] = {13u, 15u, 26u, 6u};
  uint32_t r1[4] = {17u, 29u, 16u, 24u};
  uint32_t ks[3] = {k0, k1v, ks2};
  for (int g = 0; g < 5; ++g) {
    for (int j = 0; j < 4; ++j) {
      uint32_t rr = (g & 1) ? r1[j] : r0[j];
      x0 += x1;
      x1 = (x1 << rr) | (x1 >> (32u - rr));
      x1 ^= x0;
    }
    x0 += ks[(g + 1) % 3];
    x1 += ks[(g + 2) % 3] + (uint32_t)(g + 1);
  }
  return KPc{x0, x1};
}

constexpr KPc K1K  = ctf(0u, 42u, 0u, 0u);
constexpr KPc K2K  = ctf(0u, 42u, 0u, 1u);
constexpr KPc KWIH = ctf(K1K.a, K1K.b, 0u, 0u);
constexpr KPc KBIH = ctf(K1K.a, K1K.b, 0u, 1u);
constexpr KPc KWHH = ctf(K2K.a, K2K.b, 0u, 0u);
constexpr KPc KBHH = ctf(K2K.a, K2K.b, 0u, 1u);

__device__ __forceinline__ uint32_t tf_bits(uint32_t k0, uint32_t k1v, uint32_t j) {
  KPc r = ctf(k0, k1v, 0u, j);
  return r.a ^ r.b;
}

// ---------------- float max-reduction with order-encoded uint ----------------
__device__ __forceinline__ unsigned encf(float f) {
  unsigned u = __float_as_uint(f);
  return (u & 0x80000000u) ? ~u : (u | 0x80000000u);
}
__device__ __forceinline__ float decf(unsigned e) {
  unsigned u = (e & 0x80000000u) ? (e & 0x7FFFFFFFu) : ~e;
  return __uint_as_float(u);
}

__device__ __forceinline__ void rmax_seg(const float* __restrict__ x, int n,
                                         unsigned* __restrict__ out, int rbid, int nblk) {
  unsigned best = 0u;
  for (int i = rbid * 256 + threadIdx.x; i < n; i += nblk * 256) {
    unsigned e = encf(x[i]);
    best = best > e ? best : e;
  }
  for (int off = 32; off > 0; off >>= 1) {
    unsigned o = __shfl_down(best, off, 64);
    best = best > o ? best : o;
  }
  __shared__ unsigned sm[4];
  int lane = threadIdx.x & 63, wv = threadIdx.x >> 6;
  if (lane == 0) sm[wv] = best;
  __syncthreads();
  if (threadIdx.x == 0) {
    unsigned b = sm[0];
    for (int i = 1; i < 4; ++i) b = b > sm[i] ? b : sm[i];
    atomicMax(out, b);
  }
}

__global__ void rmax_all_kernel(const float* __restrict__ wih, const float* __restrict__ whh,
                                const float* __restrict__ bih, const float* __restrict__ bhh,
                                unsigned* __restrict__ enc) {
  int b = blockIdx.x;
  if (b < 512)       rmax_seg(wih, 4 * 256 * 4096,  enc + 0, b,        512);
  else if (b < 1024) rmax_seg(whh, 4 * 1024 * 4096, enc + 1, b - 512,  512);
  else if (b < 1088) rmax_seg(bih, 16384,           enc + 2, b - 1024, 64);
  else               rmax_seg(bhh, 16384,           enc + 3, b - 1088, 64);
}

// ---------------- XLA-replicated erfinv / uniform->normal ----------------
__device__ __forceinline__ float xla_log1p(float t) {
  float small = __fmul_rn(__fadd_rn(__fmul_rn(-0.5f, t), 1.0f), t);
  float large = logf(__fadd_rn(t, 1.0f));
  return (fabsf(t) < 1e-4f) ? small : large;
}

__device__ __forceinline__ float xla_erfinv(float x) {
  float w = -xla_log1p(-__fmul_rn(x, x));
  float p;
  if (w < 5.0f) {
    float ww = __fadd_rn(w, -2.5f);
    p = 2.81022636e-08f;
    p = __fadd_rn(3.43273939e-07f, __fmul_rn(p, ww));
    p = __fadd_rn(-3.5233877e-06f, __fmul_rn(p, ww));
    p = __fadd_rn(-4.39150654e-06f, __fmul_rn(p, ww));
    p = __fadd_rn(0.00021858087f, __fmul_rn(p, ww));
    p = __fadd_rn(-0.00125372503f, __fmul_rn(p, ww));
    p = __fadd_rn(-0.00417768164f, __fmul_rn(p, ww));
    p = __fadd_rn(0.246640727f, __fmul_rn(p, ww));
    p = __fadd_rn(1.50140941f, __fmul_rn(p, ww));
  } else {
    float ww = __fadd_rn(sqrtf(w), -3.0f);
    p = -0.000200214257f;
    p = __fadd_rn(0.000100950558f, __fmul_rn(p, ww));
    p = __fadd_rn(0.00134934322f, __fmul_rn(p, ww));
    p = __fadd_rn(-0.00367342844f, __fmul_rn(p, ww));
    p = __fadd_rn(0.00573950773f, __fmul_rn(p, ww));
    p = __fadd_rn(-0.0076224613f, __fmul_rn(p, ww));
    p = __fadd_rn(0.00943887047f, __fmul_rn(p, ww));
    p = __fadd_rn(1.00167406f, __fmul_rn(p, ww));
    p = __fadd_rn(2.83297682f, __fmul_rn(p, ww));
  }
  return __fmul_rn(p, x);
}

__device__ __forceinline__ float normal_from_bits(uint32_t bits) {
  float u01 = __uint_as_float((bits >> 9) | 0x3f800000u) - 1.0f;
  const float lo = -0x1.fffffep-1f;
  float u = fmaxf(lo, __fadd_rn(__fmul_rn(u01, 2.0f), lo));
  return __fmul_rn(0x1.6a09e6p+0f, xla_erfinv(u));
}

__device__ __forceinline__ float quantw(float x) {
  float xs = fminf(fmaxf(x, -0.9921875f), 0.9921875f);
  return __fmul_rn(rintf(__fmul_rn(xs, 128.0f)), 0.0078125f);
}

// ---------------- fused preprocessing (kv/aih/ahh/bias/t0/bt) ----------------
__device__ void do_kv(const float* __restrict__ x, const float* __restrict__ ap,
                      const float* __restrict__ offp, unsigned char* __restrict__ kvT,
                      int Kdim, int bx, int by, unsigned char* sh) {
  unsigned char (*tile)[65] = (unsigned char (*)[65])sh;
  const int tid = threadIdx.x;
  const int bt = bx * 64, it = by * 64;
  const float a = ap[0], off = offp[0];
#pragma unroll
  for (int e = 0; e < 16; ++e) {
    int idx = e * 256 + tid;
    int bl = idx >> 6, il = idx & 63;
    float v = fmaxf(-a, fminf(x[(size_t)(bt + bl) * Kdim + it + il], a));
    float t = __fdiv_rn(__fadd_rn(v, off), __fmul_rn(a, 2.0f));
    int k = (int)rintf(__fmul_rn(15.0f, t));
    tile[il][bl] = (unsigned char)(k & 15);
  }
  __syncthreads();
#pragma unroll
  for (int e = 0; e < 16; ++e) {
    int idx = e * 256 + tid;
    int il = idx >> 6, bl = idx & 63;
    kvT[(size_t)(it + il) * 4096 + bt + bl] = tile[il][bl];
  }
}

__device__ void do_aih(const float* __restrict__ input, const float* __restrict__ a1p,
                       signed char* __restrict__ A, int rbid) {
  int j = rbid * 256 + threadIdx.x;
  if (j >= 4096 * 256) return;
  float a = a1p[0];
  float v = fmaxf(-a, fminf(input[j], a));
  float t = __fdiv_rn(__fadd_rn(v, a), __fmul_rn(a, 2.0f));
  int kq = (int)rintf(__fmul_rn(15.0f, t));
  A[j]                  = (signed char)((kq >> 2) & 1);
  A[1048576 + j]        = (signed char)((kq >> 1) & 1);
  A[2097152 + j]        = (signed char)(kq & 1);
}

__device__ void do_ahh(const float* __restrict__ hx, const float* __restrict__ a11p,
                       const float* __restrict__ a1p, signed char* __restrict__ A, int rbid) {
  int j = rbid * 256 + threadIdx.x;
  if (j >= 4096 * 1024) return;
  float a = a11p[0], off = a1p[0];
  float v = fmaxf(-a, fminf(hx[j], a));
  float t = __fdiv_rn(__fadd_rn(v, off), __fmul_rn(a, 2.0f));
  int kq = (int)rintf(__fmul_rn(15.0f, t));
  A[j]                      = (signed char)((kq >> 3) & 1);
  A[(size_t)(1 << 22) + j]  = (signed char)((kq >> 2) & 1);
  A[(size_t)(2 << 22) + j]  = (signed char)((kq >> 1) & 1);
  A[(size_t)(3 << 22) + j]  = (signed char)(kq & 1);
}

__device__ void do_bias(const float* __restrict__ bsrc, float* __restrict__ bq,
                        float* __restrict__ nb, int n, const unsigned* __restrict__ encp,
                        uint32_t k0, uint32_t k1v, int rbid) {
  int j = rbid * 256 + threadIdx.x;
  if (j >= n) return;
  float bmax = decf(*encp);
  float nrm = normal_from_bits(tf_bits(k0, k1v, (uint32_t)j));
  bq[j] = quantw(bsrc[j]);
  nb[j] = __fmul_rn(__fmul_rn(nrm, bmax), 0.1f);
}

__device__ void do_t0(const float* __restrict__ W, float* __restrict__ T0,
                      const unsigned* __restrict__ encp, int rbid) {
  int j = rbid * 256 + threadIdx.x;
  if (j >= 1048576) return;
  float wmax = decf(*encp);
  float nrm = normal_from_bits(tf_bits(KWIH.a, KWIH.b, (uint32_t)j));
  float nw = __fmul_rn(__fmul_rn(nrm, wmax), 0.1f);
  T0[j] = __fadd_rn(quantw(W[j]), nw);
}

__device__ void do_bt(const float* __restrict__ W, signed char* __restrict__ Bt,
                      const unsigned* __restrict__ encp, int K, int m0, int nPlanes,
                      uint32_t k0k, uint32_t k1k, int bx, int by, int bz,
                      unsigned char* sh) {
  signed char* lhi = (signed char*)sh;
  signed char* llo = (signed char*)sh + 4352;
  const int tid = threadIdx.x;
  const int m = m0 + bz;
  const int kt = by * 64, ct = bx * 64;
  const float wmax = decf(*encp);
#pragma unroll 4
  for (int i = 0; i < 16; ++i) {
    int e = i * 256 + tid;
    int kl = e >> 6, cl = e & 63;
    uint32_t j = (uint32_t)(((m * K + kt + kl) << 12) + ct + cl);
    float nrm = normal_from_bits(tf_bits(k0k, k1k, j));
    float t = __fadd_rn(quantw(W[j]), __fmul_rn(__fmul_rn(nrm, wmax), 0.1f));
    int ti = (int)rintf(__fmul_rn(t, 6144.0f));
    int hi = (ti + 128) >> 8;
    int lo = ti - (hi << 8);
    lhi[cl * 68 + kl] = (signed char)hi;
    llo[cl * 68 + kl] = (signed char)lo;
  }
  __syncthreads();
  const size_t planeElems = (size_t)K << 12;
  signed char* bh = Bt + (size_t)bz * planeElems;
  signed char* bl = Bt + (size_t)(nPlanes + bz) * planeElems;
#pragma unroll 4
  for (int i = 0; i < 16; ++i) {
    int f = i * 256 + tid;
    int cl = f >> 6, kl = f & 63;
    size_t o = (size_t)(ct + cl) * K + kt + kl;
    bh[o] = lhi[cl * 68 + kl];
    bl[o] = llo[cl * 68 + kl];
  }
}

// block ranges: kv[0,256) aih[256,4352) ahh[4352,20736) biasih[20736,20800)
// biashh[20800,20864) t0[20864,24960) bt_hh[24960,29056) bt_ih[29056,29824)
__global__ __launch_bounds__(256) void prep_all_kernel(
    const float* __restrict__ input, const float* __restrict__ hx,
    const float* __restrict__ wih, const float* __restrict__ whh,
    const float* __restrict__ bih, const float* __restrict__ bhh,
    const float* __restrict__ a1p, const float* __restrict__ a11p,
    const unsigned* __restrict__ enc,
    unsigned char* __restrict__ kvT, signed char* __restrict__ A_ih,
    signed char* __restrict__ A_hh, float* __restrict__ bq_ih, float* __restrict__ nb_ih,
    float* __restrict__ bq_hh, float* __restrict__ nb_hh, float* __restrict__ T0,
    signed char* __restrict__ Bt_hh, signed char* __restrict__ Bt_ih) {
  __shared__ __align__(16) unsigned char sh[8704];
  int b = blockIdx.x;
  if (b < 256) {
    do_kv(input, a1p, a1p, kvT, 256, b & 63, b >> 6, sh);
  } else if (b < 4352) {
    do_aih(input, a1p, A_ih, b - 256);
  } else if (b < 20736) {
    do_ahh(hx, a11p, a1p, A_hh, b - 4352);
  } else if (b < 20800) {
    do_bias(bih, bq_ih, nb_ih, 16384, enc + 2, KBIH.a, KBIH.b, b - 20736);
  } else if (b < 20864) {
    do_bias(bhh, bq_hh, nb_hh, 16384, enc + 3, KBHH.a, KBHH.b, b - 20800);
  } else if (b < 24960) {
    do_t0(wih, T0, enc + 0, b - 20864);
  } else if (b < 29056) {
    int t = b - 24960;
    do_bt(whh, Bt_hh, enc + 1, 1024, 0, 4, KWHH.a, KWHH.b, t & 63, (t >> 6) & 15, t >> 10, sh);
  } else {
    int t = b - 29056;
    do_bt(wih, Bt_ih, enc + 0, 256, 1, 3, KWIH.a, KWIH.b, t & 63, (t >> 6) & 3, t >> 8, sh);
  }
}

// ---------------- ih plane-0 GEMM: bit-exact f32, global-broadcast t feed ----
// lanes = rows, 32 cols/thread; t wave-uniform -> one broadcast transaction.
__global__ __launch_bounds__(256) void gemm_p0_kernel(
    const float* __restrict__ T0, const float* __restrict__ bq, const float* __restrict__ nb,
    const unsigned char* __restrict__ kvT, unsigned char* __restrict__ Kp) {
  const int tid = threadIdx.x, lane = tid & 63, wv = tid >> 6;
  const int c0 = blockIdx.x * 32;
  const int row = blockIdx.y * 256 + wv * 64 + lane;

  float acc[32];
#pragma unroll
  for (int j = 0; j < 32; ++j) acc[j] = 0.0f;

  const unsigned char* kvp = kvT + row;
#pragma unroll 2
  for (int k = 0; k < 256; ++k) {
    unsigned nib = kvp[(size_t)k << 12];
    float f = (float)((nib >> 3) & 1u);
    const float4* tp = (const float4*)(T0 + ((size_t)k << 12) + c0);
    float4 tv[8];
#pragma unroll
    for (int q = 0; q < 8; ++q) tv[q] = tp[q];
#pragma unroll
    for (int q = 0; q < 8; ++q) {
      acc[q * 4 + 0] = __builtin_fmaf(f, tv[q].x, acc[q * 4 + 0]);
      acc[q * 4 + 1] = __builtin_fmaf(f, tv[q].y, acc[q * 4 + 1]);
      acc[q * 4 + 2] = __builtin_fmaf(f, tv[q].z, acc[q * 4 + 2]);
      acc[q * 4 + 3] = __builtin_fmaf(f, tv[q].w, acc[q * 4 + 3]);
    }
  }

#pragma unroll
  for (int j = 0; j < 32; ++j) {
    int col = c0 + j;
    float s = __fadd_rn(__fadd_rn(acc[j], bq[col]), nb[col]);
    Kp[((size_t)row << 12) + col] = (s > 0.5f) ? (unsigned char)8 : (unsigned char)0;
  }
}

// ---------------- i8 MFMA GEMM: r7 structure (measured 193us) ----------------
// Block tile 128x64, wave tile 64x32. LDS: 3 x (128+64+64) x 64B = 48 KiB.
// XOR swizzle (bank-conflict-free, r6-verified). Depth-2 prefetch, raw
// s_barrier + s_waitcnt vmcnt(4) (tile t done, t+1's 4 loads fly across).
typedef __attribute__((address_space(3))) signed char lds_i8;
typedef __attribute__((address_space(1))) const signed char g_i8;

__device__ __forceinline__ void glds16(const signed char* g, signed char* l) {
  __builtin_amdgcn_global_load_lds((g_i8*)g, (lds_i8*)l, 16, 0, 0);
}

__global__ __launch_bounds__(256, 3) void gemm_mfma_kernel(
    const signed char* __restrict__ Ahh, const signed char* __restrict__ Bthh,
    const signed char* __restrict__ Aih, const signed char* __restrict__ Btih,
    const float* __restrict__ bqh, const float* __restrict__ nbh,
    const float* __restrict__ bqi, const float* __restrict__ nbi,
    unsigned char* __restrict__ Kp) {
  const int tid = threadIdx.x;
  const int lane = tid & 63, wv = tid >> 6;
  const int col0 = blockIdx.x * 64;
  const int row0 = blockIdx.y * 128;
  const int wrow = (wv >> 1) * 64;   // 0 / 64
  const int wcol = (wv & 1) * 32;    // 0 / 32

  // [buf][ A:128x64 | H:64x64 | L:64x64 ] bytes, triple-buffered
  __shared__ __align__(16) signed char smbuf[3][16384];
  const int HOFF = 8192, LOFF = 12288;

  const int l15 = lane & 15;
  const int cc  = (((lane >> 4) ^ ((lane >> 1) & 3)) << 4);        // frag-read chunk byte
  const int xq  = ((((lane & 3) ^ ((lane >> 3) & 3))) << 4);       // stage source chunk byte
  const int lr  = lane >> 2;                                       // stage local row 0..15

  uint32_t k12[4][2];
#pragma unroll
  for (int rf = 0; rf < 4; ++rf) { k12[rf][0] = 0u; k12[rf][1] = 0u; }

  for (int sub = 0; sub < 7; ++sub) {
    int K, w;
    const signed char *A, *Bh, *Bl;
    const float *bqp, *nbp;
    if (sub < 4) {                       // hh plane m = sub
      int m = sub;
      K = 1024;
      A  = Ahh  + ((size_t)m << 22);
      Bh = Bthh + ((size_t)m << 22);
      Bl = Bthh + ((size_t)(4 + m) << 22);
      bqp = bqh + (m << 12); nbp = nbh + (m << 12);
      w = (1 << (3 - m)) << 4;
    } else {                             // ih plane m = sub-3 (1..3)
      int m = sub - 3;
      K = 256;
      A  = Aih  + ((size_t)(m - 1) << 20);
      Bh = Btih + ((size_t)(m - 1) << 20);
      Bl = Btih + ((size_t)(3 + m - 1) << 20);
      bqp = bqi + (m << 12); nbp = nbi + (m << 12);
      w = 1 << (3 - m);
    }

    // per-lane pre-swizzled source pointers (row base mult of 16 -> the
    // (row>>1)&3 swizzle reduces to (l>>3)&3, identical for all 4 calls)
    const size_t soff = (size_t)lr * K + xq;
    const signed char* gA  = A  + (size_t)(row0 + 32 * wv) * K + soff;
    const signed char* gA2 = gA + (size_t)16 * K;
    const signed char* gH  = Bh + (size_t)(col0 + 16 * wv) * K + soff;
    const signed char* gL  = Bl + (size_t)(col0 + 16 * wv) * K + soff;

    auto stage = [&](signed char* base, int k0) {
      glds16(gA  + k0, base + (32 * wv) * 64);
      glds16(gA2 + k0, base + (32 * wv + 16) * 64);
      glds16(gH  + k0, base + HOFF + (16 * wv) * 64);
      glds16(gL  + k0, base + LOFF + (16 * wv) * 64);
    };

    v4i ach[4][2], acl[4][2];
    v4i zero = {0, 0, 0, 0};
#pragma unroll
    for (int rf = 0; rf < 4; ++rf)
#pragma unroll
      for (int cf = 0; cf < 2; ++cf) { ach[rf][cf] = zero; acl[rf][cf] = zero; }

    signed char* bc = &smbuf[0][0];      // current (tile t)
    signed char* bn = &smbuf[1][0];      // next (tile t+1)
    signed char* bf = &smbuf[2][0];      // free (target for tile t+2)

    const int nt = K >> 6;
    stage(bc, 0);
    stage(bn, 64);

    for (int t = 0; t < nt; ++t) {
      if (t + 1 < nt) {
        asm volatile("s_waitcnt vmcnt(4)" ::: "memory");   // tile t done, t+1 flies
      } else {
        asm volatile("s_waitcnt vmcnt(0)" ::: "memory");   // last tile: full drain
      }
      __builtin_amdgcn_s_barrier();
      __builtin_amdgcn_sched_barrier(0);
      if (t + 2 < nt) stage(bf, (t + 2) << 6);             // newest 4, fly across barriers

      v4i af[4], bfh[2], bfl[2];
#pragma unroll
      for (int rf = 0; rf < 4; ++rf)
        af[rf] = *(const v4i*)(bc + (wrow + rf * 16 + l15) * 64 + cc);
#pragma unroll
      for (int cf = 0; cf < 2; ++cf) {
        bfh[cf] = *(const v4i*)(bc + HOFF + (wcol + cf * 16 + l15) * 64 + cc);
        bfl[cf] = *(const v4i*)(bc + LOFF + (wcol + cf * 16 + l15) * 64 + cc);
      }
#pragma unroll
      for (int rf = 0; rf < 4; ++rf)
#pragma unroll
        for (int cf = 0; cf < 2; ++cf) {
          ach[rf][cf] = __builtin_amdgcn_mfma_i32_16x16x64_i8(af[rf], bfh[cf], ach[rf][cf], 0, 0, 0);
          acl[rf][cf] = __builtin_amdgcn_mfma_i32_16x16x64_i8(af[rf], bfl[cf], acl[rf][cf], 0, 0, 0);
        }
      signed char* tmp = bc; bc = bn; bn = bf; bf = tmp;   // rotate buffers
    }
    __syncthreads();                     // sub boundary: reads done, safe restage

    // epilogue: float math bit-identical to round 5; pack decision bits per r
#pragma unroll
    for (int cf = 0; cf < 2; ++cf) {
      int col = col0 + wcol + cf * 16 + l15;
      float bqc = bqp[col];
      float nbc = nbp[col];
#pragma unroll
      for (int rf = 0; rf < 4; ++rf)
#pragma unroll
        for (int r = 0; r < 4; ++r) {
          int tot = ach[rf][cf][r] * 256 + acl[rf][cf][r];
          float s = __fmul_rn((float)tot, (1.0f / 6144.0f));
          float s2 = __fadd_rn(__fadd_rn(s, bqc), nbc);
          if (s2 > 0.5f) k12[rf][cf] += ((uint32_t)w << (8 * r));
        }
    }
  }

  // RMW-or bits into Kp (plane-0 kernel already stored bit 3; stream-ordered)
#pragma unroll
  for (int rf = 0; rf < 4; ++rf)
#pragma unroll
    for (int cf = 0; cf < 2; ++cf)
#pragma unroll
      for (int r = 0; r < 4; ++r) {
        int row = row0 + wrow + rf * 16 + ((lane >> 4) << 2) + r;
        int col = col0 + wcol + cf * 16 + l15;
        size_t o = ((size_t)row << 12) + col;
        Kp[o] = (unsigned char)(Kp[o] | ((k12[rf][cf] >> (8 * r)) & 255u));
      }
}

// ---------------- elementwise tail: LDS tables for all transcendentals ------
// gate() inputs take only 256 lattice values; nc only 255 quantized values.
// Tables computed per-block with the EXACT double expressions of round 5
// -> bit-identical outputs. Grid-stride 2048 blocks amortizes table cost.
__device__ __forceinline__ float quant8(float x, float r) {
  float xs = __fdiv_rn(x, r);
  xs = fminf(fmaxf(xs, -0.9921875f), 0.9921875f);
  float q = rintf(__fmul_rn(xs, 128.0f));
  return __fmul_rn(__fdiv_rn(q, 128.0f), r);
}
__device__ __forceinline__ float pactf(float x, float a) { return fminf(fmaxf(x, -a), a); }
__device__ __forceinline__ double sigd(double x) { return 1.0 / (1.0 + exp(-x)); }

__global__ __launch_bounds__(256) void tail_kernel(
    const unsigned char* __restrict__ Kp, const float* __restrict__ cx,
    const float* a1p, const float* a3p, const float* a4p,
    const float* a5p, const float* a6p, const float* a7p,
    const float* a8p, const float* a9p, const float* a10p,
    const float* a11p, float* __restrict__ out) {
  __shared__ float Tf[256], Ti[256], Tj[256], To[256], Tac[256];
  const int tid = threadIdx.x;
  const double a1 = (double)a1p[0], a11 = (double)a11p[0];
  const float a3 = a3p[0], a4 = a4p[0], a5 = a5p[0], a6 = a6p[0];
  const float a7 = a7p[0], a8 = a8p[0], a9 = a9p[0], a10 = a10p[0], a11f = a11p[0];

  {
    int pk = tid;
    double s1 = (double)(pk & 15) * (1.0 / 15.0);
    double s2 = (double)(pk >> 4) * (1.0 / 15.0);
    double g = (s1 * (2.0 * a1) - a1) + (s2 * (2.0 * a11) - a11);
    Tf[pk] = quant8(pactf((float)sigd(g), a3), a3);
    Ti[pk] = quant8(pactf((float)sigd(g), a4), a4);
    Tj[pk] = quant8(pactf((float)tanh(g), a5), a5);
    To[pk] = quant8(pactf((float)sigd(g), a6), a6);
    if (tid < 255) {
      float qf = (float)(tid - 127);                       // q in [-127,127]
      float ncv = __fmul_rn(__fdiv_rn(qf, 128.0f), a9);
      Tac[tid] = quant8(pactf((float)tanh((double)ncv), a10), a10);
    }
  }
  __syncthreads();

  for (int idx = blockIdx.x * 256 + tid; idx < 4194304; idx += 2048 * 256) {
    int b = idx >> 10, h = idx & 1023;
    const unsigned char* row = Kp + (size_t)b * 4096 + h;
    int pI = row[0], pJ = row[1024], pF = row[2048], pO = row[3072];
    float fg  = Tf[pF];
    float ig  = Ti[pI];
    float act = Tj[pJ];
    float og  = To[pO];
    float cxv = cx[idx];
    float gc  = quant8(pactf(__fmul_rn(cxv, fg), a7), a7);
    float ai  = quant8(pactf(__fmul_rn(ig, act), a8), a8);
    // nc = quant8(pactf(gc+ai, a9), a9), with integer grid index exposed
    float s   = __fadd_rn(gc, ai);
    float xs  = fminf(fmaxf(__fdiv_rn(pactf(s, a9), a9), -0.9921875f), 0.9921875f);
    float qf  = rintf(__fmul_rn(xs, 128.0f));
    float nc  = __fmul_rn(__fdiv_rn(qf, 128.0f), a9);
    float ac  = Tac[(int)qf + 127];
    float nh  = quant8(pactf(__fmul_rn(ac, og), a11f), a11f);
    out[idx] = nh;
    out[4194304 + idx] = nc;
  }
}

// ============================================================================
extern "C" void kernel_launch(void* const* d_in, const int* in_sizes, int n_in,
                              void* d_out, int out_size, void* d_ws, size_t ws_size,
                              hipStream_t stream) {
  const float* input = (const float*)d_in[0];
  const float* hx    = (const float*)d_in[1];
  const float* cx    = (const float*)d_in[2];
  const float* wih   = (const float*)d_in[3];
  const float* whh   = (const float*)d_in[4];
  const float* bih   = (const float*)d_in[5];
  const float* bhh   = (const float*)d_in[6];
  const float* a1p   = (const float*)d_in[7];
  const float* a3p   = (const float*)d_in[8];
  const float* a4p   = (const float*)d_in[9];
  const float* a5p   = (const float*)d_in[10];
  const float* a6p   = (const float*)d_in[11];
  const float* a7p   = (const float*)d_in[12];
  const float* a8p   = (const float*)d_in[13];
  const float* a9p   = (const float*)d_in[14];
  const float* a10p  = (const float*)d_in[15];
  const float* a11p  = (const float*)d_in[16];

  char* ws = (char*)d_ws;
  unsigned* enc        = (unsigned*)ws;                            // 256 B
  float* T0            = (float*)(ws + 256);                       // 4 MiB  [256][4096]
  float* bq_ih         = (float*)(ws + 256 + 4194304);             // 64 KiB x4
  float* nb_ih         = bq_ih + 16384;
  float* bq_hh         = nb_ih + 16384;
  float* nb_hh         = bq_hh + 16384;
  unsigned char* kv_ih = (unsigned char*)(nb_hh + 16384);          // 1 MiB [256][4096]
  signed char* A_hh    = (signed char*)(kv_ih + 1048576);          // 16 MiB [4][4096][1024]
  signed char* Bt_hh   = A_hh + 16777216;                          // 32 MiB [2][4][4096][1024]
  signed char* A_ih    = Bt_hh + 33554432;                         // 3 MiB [3][4096][256]
  signed char* Bt_ih   = A_ih + 3145728;                           // 6 MiB [2][3][4096][256]
  unsigned char* Kp    = (unsigned char*)(Bt_ih + 6291456);        // 16 MiB
  // total ~78.3 MiB

  hipMemsetAsync(enc, 0, 64, stream);

  rmax_all_kernel<<<1152, 256, 0, stream>>>(wih, whh, bih, bhh, enc);

  prep_all_kernel<<<29824, 256, 0, stream>>>(input, hx, wih, whh, bih, bhh, a1p, a11p,
                                             enc, kv_ih, A_ih, A_hh, bq_ih, nb_ih,
                                             bq_hh, nb_hh, T0, Bt_hh, Bt_ih);

  gemm_p0_kernel<<<dim3(128, 16), 256, 0, stream>>>(T0, bq_ih, nb_ih, kv_ih, Kp);
  gemm_mfma_kernel<<<dim3(64, 32), 256, 0, stream>>>(A_hh, Bt_hh, A_ih, Bt_ih,
                                                     bq_hh, nb_hh, bq_ih, nb_ih, Kp);

  tail_kernel<<<2048, 256, 0, stream>>>(Kp, cx, a1p, a3p, a4p, a5p, a6p, a7p, a8p, a9p,
                                        a10p, a11p, (float*)d_out);
}